// Round 1
// baseline (308.301 us; speedup 1.0000x reference)
//
#include <hip/hip_runtime.h>
#include <math.h>

// Chamfer distance, B=2, N=M=8192, C=3, fp32 — FUSED: each d(s_i,t_j) computed once,
// feeding both row-min (src->tgt) and col-min (tgt->src).
// d_out (float32): [loss_src, loss_dst, indices1 (B*N), indices2 (B*M)]
// ws: u64[32768]: [0,16384) row packed (dist<<32|colBatchBase), [16384,32768) col packed
//     (dist<<32|rowAnchor); then float pr[64], pc[4096]; then u32 ticket counter.

static constexpr int Bn = 2;
static constexpr int Nn = 8192;
static constexpr int THR = 256;    // 4 waves per block
static constexpr int QPL = 4;      // rows per lane
static constexpr int RT = 1024;    // rows per block; wave w owns [rbase+256w, +256)
static constexpr int WROWS = 256;  // rows per wave (QPL*64)
static constexpr int CT = 128;     // cols staged per block (64 -> 128: halves row atomics)
static constexpr int TB = 8;       // cols per register batch
static constexpr int CB = 4096;    // col-mode blocks in cd_fin (4 cols/block, 1 wave/col)
static constexpr int FINB = CB + 64;

__device__ __forceinline__ float dist3(float s0, float s1, float s2,
                                       float q0, float q1, float q2) {
    #pragma clang fp contract(off)
    float d0 = s0 - q0;
    float d1 = s1 - q1;
    float d2 = s2 - q2;
    return (d0 * d0 + d1 * d1) + d2 * d2;   // numpy-exact rounding order
}

__global__ void cd_init(unsigned long long* __restrict__ ws,
                        unsigned int* __restrict__ cnt) {
    int i = blockIdx.x * blockDim.x + threadIdx.x;
    if (i < 2 * Bn * Nn) ws[i] = 0xFFFFFFFFFFFFFFFFULL;
    if (i == 0) *cnt = 0u;
}

__global__ __launch_bounds__(THR) void cd_tile(const float* __restrict__ S,
                                               const float* __restrict__ T,
                                               unsigned long long* __restrict__ ws) {
    const int b = blockIdx.z;
    const int rbase = blockIdx.x * RT;
    const int cbase = blockIdx.y * CT;
    unsigned long long* wsRow = ws + (size_t)b * Nn;
    unsigned long long* wsCol = ws + 2 * Nn + (size_t)b * Nn;

    __shared__ alignas(16) float lq[CT * 3];            // 384 floats = 1.5 KB
    __shared__ unsigned long long lwcol[4][CT];         // per-wave col minima, 4 KB
    if (threadIdx.x < CT * 3 / 4)                       // 96 float4 stores
        ((float4*)lq)[threadIdx.x] =
            ((const float4*)(T + ((size_t)b * Nn + cbase) * 3))[threadIdx.x];
    __syncthreads();

    const int w = threadIdx.x >> 6;
    const int L = threadIdx.x & 63;
    const int rowA = rbase + w * WROWS + L;        // + k*64, k<QPL
    const unsigned int anchor = (unsigned int)(rbase + w * WROWS);

    float q0[QPL], q1[QPL], q2[QPL];
    #pragma unroll
    for (int k = 0; k < QPL; ++k) {
        const float* p = S + ((size_t)b * Nn + rowA + k * 64) * 3;
        q0[k] = p[0]; q1[k] = p[1]; q2[k] = p[2];
    }

    float best[QPL];
    int bb[QPL];
    #pragma unroll
    for (int k = 0; k < QPL; ++k) { best[k] = INFINITY; bb[k] = 0; }

    const float4* lq4 = (const float4*)lq;
    #pragma unroll 2
    for (int jb = 0; jb < CT / TB; ++jb) {
        float4 v[6];                       // 24 floats = 8 target points
        #pragma unroll
        for (int j = 0; j < 6; ++j) v[j] = lq4[jb * 6 + j];

        float cm[TB];
        #define COMP(k) ((k & 3) == 0 ? v[(k) >> 2].x : \
                         (k & 3) == 1 ? v[(k) >> 2].y : \
                         (k & 3) == 2 ? v[(k) >> 2].z : v[(k) >> 2].w)
        #pragma unroll
        for (int k = 0; k < QPL; ++k) {
            float d[TB];
            #pragma unroll
            for (int t = 0; t < TB; ++t)
                d[t] = dist3(q0[k], q1[k], q2[k],
                             COMP(3 * t), COMP(3 * t + 1), COMP(3 * t + 2));
            // col side: running min over this lane's rows (exact fmin)
            #pragma unroll
            for (int t = 0; t < TB; ++t)
                cm[t] = (k == 0) ? d[t] : fminf(cm[t], d[t]);
            // row side: exact associative tree (shapes to v_min3) + strict <
            float m0 = fminf(fminf(d[0], d[1]), d[2]);
            float m1 = fminf(fminf(d[3], d[4]), d[5]);
            float m2 = fminf(d[6], d[7]);
            float bmin = fminf(fminf(m0, m1), m2);
            if (bmin < best[k]) { best[k] = bmin; bb[k] = cbase + jb * TB; }
        }
        #undef COMP

        // Fold-reduce 8 cols x 64 lanes -> lane L holds col 4*(L&1)+2*((L>>1)&1)+((L>>2)&1).
        // Exact: fmin only, any order gives the identical min value.
        const bool u1 = (L & 1);
        float a0 = fminf(u1 ? cm[4] : cm[0], __shfl_xor(u1 ? cm[0] : cm[4], 1, 64));
        float a1 = fminf(u1 ? cm[5] : cm[1], __shfl_xor(u1 ? cm[1] : cm[5], 1, 64));
        float a2 = fminf(u1 ? cm[6] : cm[2], __shfl_xor(u1 ? cm[2] : cm[6], 1, 64));
        float a3 = fminf(u1 ? cm[7] : cm[3], __shfl_xor(u1 ? cm[3] : cm[7], 1, 64));
        const bool u2 = (L & 2);
        float b0 = fminf(u2 ? a2 : a0, __shfl_xor(u2 ? a0 : a2, 2, 64));
        float b1 = fminf(u2 ? a3 : a1, __shfl_xor(u2 ? a1 : a3, 2, 64));
        const bool u4 = (L & 4);
        float c0 = fminf(u4 ? b1 : b0, __shfl_xor(u4 ? b0 : b1, 4, 64));
        c0 = fminf(c0, __shfl_xor(c0, 8, 64));
        c0 = fminf(c0, __shfl_xor(c0, 16, 64));
        c0 = fminf(c0, __shfl_xor(c0, 32, 64));

        if (L < TB) {
            const int c = 4 * (L & 1) + 2 * ((L >> 1) & 1) + ((L >> 2) & 1);
            unsigned long long pk =
                ((unsigned long long)__float_as_uint(c0) << 32) | anchor;
            // Per-wave slot, written exactly once per block -> plain store, no atomic.
            lwcol[w][jb * TB + c] = pk;
        }
    }

    // Row side: one device atomic per (row, col-block) = B*N^2/CT total.
    #pragma unroll
    for (int k = 0; k < QPL; ++k) {
        unsigned long long pk =
            ((unsigned long long)__float_as_uint(best[k]) << 32) |
            (unsigned int)bb[k];
        atomicMin(&wsRow[rowA + k * 64], pk);
    }

    // Col side: cross-wave min in LDS, then ONE device atomic per col per block.
    __syncthreads();
    if (threadIdx.x < CT) {
        unsigned long long x0 = lwcol[0][threadIdx.x];
        unsigned long long x1 = lwcol[1][threadIdx.x];
        unsigned long long x2 = lwcol[2][threadIdx.x];
        unsigned long long x3 = lwcol[3][threadIdx.x];
        unsigned long long m01 = x0 < x1 ? x0 : x1;
        unsigned long long m23 = x2 < x3 ? x2 : x3;
        unsigned long long m = m01 < m23 ? m01 : m23;
        atomicMin(&wsCol[cbase + threadIdx.x], m);
    }
}

// Merged epilogue. Blocks [0,CB): col mode, 1 wave per col entry (coalesced float4
// scan of the 256-row anchor range). Blocks [CB, CB+64): row mode, 1 thread per row
// entry (float4 target batch, descending == scan). Last-arriving block performs the
// deterministic combine (same fixed strided order as the old cd_combine kernel).
__global__ __launch_bounds__(256) void cd_fin(const unsigned long long* __restrict__ ws,
                                              const float* __restrict__ S,
                                              const float* __restrict__ T,
                                              float* __restrict__ out,
                                              float* __restrict__ pr,
                                              float* __restrict__ pc,
                                              unsigned int* __restrict__ cnt) {
    __shared__ float red[4];
    __shared__ float r1[4], r2[4];
    __shared__ int amLast;
    const int tid = threadIdx.x;

    if (blockIdx.x < CB) {   // ---- col mode ----
        const int e = blockIdx.x * 4 + (tid >> 6);   // col entry [0, 16384)
        const int L = tid & 63;
        const int b = e >> 13;
        const int col = e & 8191;

        unsigned long long p = ws[2 * Nn + e];
        const float m = __uint_as_float((unsigned int)(p >> 32));
        const int A = (int)(unsigned int)(p & 0xFFFFFFFFu);

        const float* tc = T + ((size_t)b * Nn + col) * 3;
        const float t0 = tc[0], t1 = tc[1], t2 = tc[2];

        const float4* Sp = (const float4*)(S + ((size_t)b * Nn + A + L * 4) * 3);
        const float4 x0 = Sp[0], x1 = Sp[1], x2 = Sp[2];   // 4 rows, coalesced

        int found = 0x7FFFFFFF;
        // descending r: last write wins -> smallest r; then int-min across lanes.
        if (dist3(x2.y, x2.z, x2.w, t0, t1, t2) == m) found = A + L * 4 + 3;
        if (dist3(x1.z, x1.w, x2.x, t0, t1, t2) == m) found = A + L * 4 + 2;
        if (dist3(x0.w, x1.x, x1.y, t0, t1, t2) == m) found = A + L * 4 + 1;
        if (dist3(x0.x, x0.y, x0.z, t0, t1, t2) == m) found = A + L * 4 + 0;
        #pragma unroll
        for (int mask = 1; mask < 64; mask <<= 1)
            found = min(found, __shfl_xor(found, mask, 64));
        if (L == 0) out[2 + 2 * Nn + e] = (float)found;

        if (L == 0) red[tid >> 6] = m;
        __syncthreads();
        if (tid == 0) pc[blockIdx.x] = (red[0] + red[1]) + (red[2] + red[3]);
    } else {                 // ---- row mode ----
        const int j = (blockIdx.x - CB) * 256 + tid;   // [0, 16384)
        const int b = j >> 13;
        const int row = j & 8191;

        unsigned long long p = ws[j];
        const float dist = __uint_as_float((unsigned int)(p >> 32));
        const int cb = (int)(unsigned int)(p & 0xFFFFFFFFu);

        const float* Pp = S + ((size_t)b * Nn + row) * 3;
        const float s0 = Pp[0], s1 = Pp[1], s2 = Pp[2];
        const float4* Qb = (const float4*)(T + ((size_t)b * Nn + cb) * 3);  // cb%8==0 -> aligned
        const float4 y0 = Qb[0], y1 = Qb[1], y2 = Qb[2];
        const float4 y3 = Qb[3], y4 = Qb[4], y5 = Qb[5];

        int idx = cb;
        // descending t: last write wins -> smallest t attaining dist.
        if (dist3(s0, s1, s2, y5.y, y5.z, y5.w) == dist) idx = cb + 7;
        if (dist3(s0, s1, s2, y4.z, y4.w, y5.x) == dist) idx = cb + 6;
        if (dist3(s0, s1, s2, y3.w, y4.x, y4.y) == dist) idx = cb + 5;
        if (dist3(s0, s1, s2, y3.x, y3.y, y3.z) == dist) idx = cb + 4;
        if (dist3(s0, s1, s2, y2.y, y2.z, y2.w) == dist) idx = cb + 3;
        if (dist3(s0, s1, s2, y1.z, y1.w, y2.x) == dist) idx = cb + 2;
        if (dist3(s0, s1, s2, y0.w, y1.x, y1.y) == dist) idx = cb + 1;
        if (dist3(s0, s1, s2, y0.x, y0.y, y0.z) == dist) idx = cb + 0;
        out[2 + j] = (float)idx;

        float sum = dist;
        for (int off = 32; off > 0; off >>= 1) sum += __shfl_down(sum, off, 64);
        if ((tid & 63) == 0) red[tid >> 6] = sum;
        __syncthreads();
        if (tid == 0)
            pr[blockIdx.x - CB] = (red[0] + red[1]) + (red[2] + red[3]);
    }

    // ---- fused deterministic combine: last block to arrive does it ----
    __threadfence();                       // make pr/pc stores visible device-wide
    if (tid == 0)
        amLast = (atomicAdd(cnt, 1u) == (unsigned int)(FINB - 1));
    __syncthreads();
    if (amLast) {
        __threadfence();                   // acquire: see all other blocks' partials
        float s1 = (tid < 64) ? pr[tid] : 0.0f;
        float s2 = 0.0f;
        for (int i = tid; i < CB; i += 256) s2 += pc[i];   // fixed strided order
        for (int off = 32; off > 0; off >>= 1) {
            s1 += __shfl_down(s1, off, 64);
            s2 += __shfl_down(s2, off, 64);
        }
        if ((tid & 63) == 0) { r1[tid >> 6] = s1; r2[tid >> 6] = s2; }
        __syncthreads();
        if (tid == 0) {
            out[0] = ((r1[0] + r1[1]) + (r1[2] + r1[3])) / (float)(Bn * Nn);
            out[1] = ((r2[0] + r2[1]) + (r2[2] + r2[3])) / (float)(Bn * Nn);
        }
    }
}

// Fallback (no workspace): scan-all per query, direct writes + atomic loss.
static constexpr int FPTS = 256;
static constexpr int FCHUNK = 1024;

__global__ void cd_zero2(float* __restrict__ out) { out[0] = 0.0f; out[1] = 0.0f; }

__global__ __launch_bounds__(FPTS) void cd_dir_direct(const float* __restrict__ P,
                                                      const float* __restrict__ Q,
                                                      int nP, int nQ,
                                                      float* __restrict__ idx_out,
                                                      float* __restrict__ loss_out,
                                                      float inv_count) {
    __shared__ float lq[FCHUNK * 3];
    __shared__ float red[FPTS / 64];
    const int b = blockIdx.z;
    const int i = blockIdx.x * FPTS + threadIdx.x;
    const float* Pp = P + ((size_t)b * nP + i) * 3;
    const float s0 = Pp[0], s1 = Pp[1], s2 = Pp[2];

    float best = INFINITY;
    int bi = 0;
    for (int c = 0; c < nQ / FCHUNK; ++c) {
        __syncthreads();
        const float* Qb = Q + ((size_t)b * nQ + (size_t)c * FCHUNK) * 3;
        for (int j = threadIdx.x; j < FCHUNK * 3; j += FPTS) lq[j] = Qb[j];
        __syncthreads();
        #pragma unroll 4
        for (int m = 0; m < FCHUNK; ++m) {
            float dist = dist3(s0, s1, s2, lq[3 * m], lq[3 * m + 1], lq[3 * m + 2]);
            if (dist < best) { best = dist; bi = c * FCHUNK + m; }
        }
    }
    idx_out[(size_t)b * nP + i] = (float)bi;

    float v = best;
    for (int off = 32; off > 0; off >>= 1) v += __shfl_down(v, off, 64);
    const int wid = threadIdx.x >> 6;
    if ((threadIdx.x & 63) == 0) red[wid] = v;
    __syncthreads();
    if (threadIdx.x == 0) {
        float a = 0.0f;
        for (int w = 0; w < FPTS / 64; ++w) a += red[w];
        atomicAdd(loss_out, a * inv_count);
    }
}

extern "C" void kernel_launch(void* const* d_in, const int* in_sizes, int n_in,
                              void* d_out, int out_size, void* d_ws, size_t ws_size,
                              hipStream_t stream) {
    const float* src = (const float*)d_in[0];
    const float* tgt = (const float*)d_in[1];
    float* out = (float*)d_out;
    const int TOTAL = 2 * Bn * Nn;                         // 32768 packed entries
    const size_t need = (size_t)TOTAL * sizeof(unsigned long long)
                      + (64 + CB) * sizeof(float) + sizeof(unsigned int);

    if (ws_size >= need) {
        unsigned long long* ws = (unsigned long long*)d_ws;
        float* pr = (float*)(ws + TOTAL);                  // 64 row partials
        float* pc = pr + 64;                               // 4096 col partials
        unsigned int* cnt = (unsigned int*)(pc + CB);      // fin-ticket counter
        cd_init<<<(TOTAL + 255) / 256, 256, 0, stream>>>(ws, cnt);
        cd_tile<<<dim3(Nn / RT, Nn / CT, Bn), THR, 0, stream>>>(src, tgt, ws);
        cd_fin<<<FINB, 256, 0, stream>>>(ws, src, tgt, out, pr, pc, cnt);
    } else {
        cd_zero2<<<1, 1, 0, stream>>>(out);
        cd_dir_direct<<<dim3(Nn / FPTS, 1, Bn), FPTS, 0, stream>>>(
            src, tgt, Nn, Nn, out + 2, out + 0, 1.0f / (float)(Bn * Nn));
        cd_dir_direct<<<dim3(Nn / FPTS, 1, Bn), FPTS, 0, stream>>>(
            tgt, src, Nn, Nn, out + 2 + Bn * Nn, out + 1, 1.0f / (float)(Bn * Nn));
    }
}

// Round 2
// 53.071 us; speedup vs baseline: 5.8092x; 5.8092x over previous
//
#include <hip/hip_runtime.h>
#include <math.h>

// Chamfer distance, B=2, N=M=8192, C=3, fp32 — FUSED: each d(s_i,t_j) computed once,
// feeding both row-min (src->tgt) and col-min (tgt->src).
// d_out (float32): [loss_src, loss_dst, indices1 (B*N), indices2 (B*M)]
// ws: u64[32768]: [0,16384) row packed (dist<<32|colBatchBase), [16384,32768) col packed
//     (dist<<32|rowAnchor); then float pr[64], pc[4096].
//
// NOTE (R1 post-mortem): do NOT fuse the final combine via a last-block ticket —
// per-block __threadfence() on multi-XCD gfx950 triggers an L2 writeback per block
// (4160 blocks -> 268 us). The kernel boundary is the cheap device-wide fence.

static constexpr int Bn = 2;
static constexpr int Nn = 8192;
static constexpr int THR = 256;    // 4 waves per block
static constexpr int QPL = 4;      // rows per lane
static constexpr int RT = 1024;    // rows per block; wave w owns [rbase+256w, +256)
static constexpr int WROWS = 256;  // rows per wave (QPL*64)
static constexpr int CT = 128;     // cols staged per block (64 -> 128: halves row atomics)
static constexpr int TB = 8;       // cols per register batch
static constexpr int CB = 4096;    // col-mode blocks in cd_fin (4 cols/block, 1 wave/col)

__device__ __forceinline__ float dist3(float s0, float s1, float s2,
                                       float q0, float q1, float q2) {
    #pragma clang fp contract(off)
    float d0 = s0 - q0;
    float d1 = s1 - q1;
    float d2 = s2 - q2;
    return (d0 * d0 + d1 * d1) + d2 * d2;   // numpy-exact rounding order
}

__global__ void cd_init(unsigned long long* __restrict__ ws) {
    int i = blockIdx.x * blockDim.x + threadIdx.x;
    if (i < 2 * Bn * Nn) ws[i] = 0xFFFFFFFFFFFFFFFFULL;
}

__global__ __launch_bounds__(THR) void cd_tile(const float* __restrict__ S,
                                               const float* __restrict__ T,
                                               unsigned long long* __restrict__ ws) {
    const int b = blockIdx.z;
    const int rbase = blockIdx.x * RT;
    const int cbase = blockIdx.y * CT;
    unsigned long long* wsRow = ws + (size_t)b * Nn;
    unsigned long long* wsCol = ws + 2 * Nn + (size_t)b * Nn;

    __shared__ alignas(16) float lq[CT * 3];            // 384 floats = 1.5 KB
    __shared__ unsigned long long lwcol[4][CT];         // per-wave col minima, 4 KB
    if (threadIdx.x < CT * 3 / 4)                       // 96 float4 stores
        ((float4*)lq)[threadIdx.x] =
            ((const float4*)(T + ((size_t)b * Nn + cbase) * 3))[threadIdx.x];
    __syncthreads();

    const int w = threadIdx.x >> 6;
    const int L = threadIdx.x & 63;
    const int rowA = rbase + w * WROWS + L;        // + k*64, k<QPL
    const unsigned int anchor = (unsigned int)(rbase + w * WROWS);

    float q0[QPL], q1[QPL], q2[QPL];
    #pragma unroll
    for (int k = 0; k < QPL; ++k) {
        const float* p = S + ((size_t)b * Nn + rowA + k * 64) * 3;
        q0[k] = p[0]; q1[k] = p[1]; q2[k] = p[2];
    }

    float best[QPL];
    int bb[QPL];
    #pragma unroll
    for (int k = 0; k < QPL; ++k) { best[k] = INFINITY; bb[k] = 0; }

    const float4* lq4 = (const float4*)lq;
    #pragma unroll 2
    for (int jb = 0; jb < CT / TB; ++jb) {
        float4 v[6];                       // 24 floats = 8 target points
        #pragma unroll
        for (int j = 0; j < 6; ++j) v[j] = lq4[jb * 6 + j];

        float cm[TB];
        #define COMP(k) ((k & 3) == 0 ? v[(k) >> 2].x : \
                         (k & 3) == 1 ? v[(k) >> 2].y : \
                         (k & 3) == 2 ? v[(k) >> 2].z : v[(k) >> 2].w)
        #pragma unroll
        for (int k = 0; k < QPL; ++k) {
            float d[TB];
            #pragma unroll
            for (int t = 0; t < TB; ++t)
                d[t] = dist3(q0[k], q1[k], q2[k],
                             COMP(3 * t), COMP(3 * t + 1), COMP(3 * t + 2));
            // col side: running min over this lane's rows (exact fmin)
            #pragma unroll
            for (int t = 0; t < TB; ++t)
                cm[t] = (k == 0) ? d[t] : fminf(cm[t], d[t]);
            // row side: exact associative tree (shapes to v_min3) + strict <
            float m0 = fminf(fminf(d[0], d[1]), d[2]);
            float m1 = fminf(fminf(d[3], d[4]), d[5]);
            float m2 = fminf(d[6], d[7]);
            float bmin = fminf(fminf(m0, m1), m2);
            if (bmin < best[k]) { best[k] = bmin; bb[k] = cbase + jb * TB; }
        }
        #undef COMP

        // Fold-reduce 8 cols x 64 lanes -> lane L holds col 4*(L&1)+2*((L>>1)&1)+((L>>2)&1).
        // Exact: fmin only, any order gives the identical min value.
        const bool u1 = (L & 1);
        float a0 = fminf(u1 ? cm[4] : cm[0], __shfl_xor(u1 ? cm[0] : cm[4], 1, 64));
        float a1 = fminf(u1 ? cm[5] : cm[1], __shfl_xor(u1 ? cm[1] : cm[5], 1, 64));
        float a2 = fminf(u1 ? cm[6] : cm[2], __shfl_xor(u1 ? cm[2] : cm[6], 1, 64));
        float a3 = fminf(u1 ? cm[7] : cm[3], __shfl_xor(u1 ? cm[3] : cm[7], 1, 64));
        const bool u2 = (L & 2);
        float b0 = fminf(u2 ? a2 : a0, __shfl_xor(u2 ? a0 : a2, 2, 64));
        float b1 = fminf(u2 ? a3 : a1, __shfl_xor(u2 ? a1 : a3, 2, 64));
        const bool u4 = (L & 4);
        float c0 = fminf(u4 ? b1 : b0, __shfl_xor(u4 ? b0 : b1, 4, 64));
        c0 = fminf(c0, __shfl_xor(c0, 8, 64));
        c0 = fminf(c0, __shfl_xor(c0, 16, 64));
        c0 = fminf(c0, __shfl_xor(c0, 32, 64));

        if (L < TB) {
            const int c = 4 * (L & 1) + 2 * ((L >> 1) & 1) + ((L >> 2) & 1);
            unsigned long long pk =
                ((unsigned long long)__float_as_uint(c0) << 32) | anchor;
            // Per-wave slot, written exactly once per block -> plain store, no atomic.
            lwcol[w][jb * TB + c] = pk;
        }
    }

    // Row side: one device atomic per (row, col-block) = B*N^2/CT total.
    #pragma unroll
    for (int k = 0; k < QPL; ++k) {
        unsigned long long pk =
            ((unsigned long long)__float_as_uint(best[k]) << 32) |
            (unsigned int)bb[k];
        atomicMin(&wsRow[rowA + k * 64], pk);
    }

    // Col side: cross-wave min in LDS, then ONE device atomic per col per block.
    __syncthreads();
    if (threadIdx.x < CT) {
        unsigned long long x0 = lwcol[0][threadIdx.x];
        unsigned long long x1 = lwcol[1][threadIdx.x];
        unsigned long long x2 = lwcol[2][threadIdx.x];
        unsigned long long x3 = lwcol[3][threadIdx.x];
        unsigned long long m01 = x0 < x1 ? x0 : x1;
        unsigned long long m23 = x2 < x3 ? x2 : x3;
        unsigned long long m = m01 < m23 ? m01 : m23;
        atomicMin(&wsCol[cbase + threadIdx.x], m);
    }
}

// Merged epilogue. Blocks [0,CB): col mode, 1 wave per col entry (coalesced float4
// scan of the 256-row anchor range). Blocks [CB, CB+64): row mode, 1 thread per row
// entry (float4 target batch, descending == scan).
__global__ __launch_bounds__(256) void cd_fin(const unsigned long long* __restrict__ ws,
                                              const float* __restrict__ S,
                                              const float* __restrict__ T,
                                              float* __restrict__ out,
                                              float* __restrict__ pr,
                                              float* __restrict__ pc) {
    __shared__ float red[4];
    const int tid = threadIdx.x;

    if (blockIdx.x < CB) {   // ---- col mode ----
        const int e = blockIdx.x * 4 + (tid >> 6);   // col entry [0, 16384)
        const int L = tid & 63;
        const int b = e >> 13;
        const int col = e & 8191;

        unsigned long long p = ws[2 * Nn + e];
        const float m = __uint_as_float((unsigned int)(p >> 32));
        const int A = (int)(unsigned int)(p & 0xFFFFFFFFu);

        const float* tc = T + ((size_t)b * Nn + col) * 3;
        const float t0 = tc[0], t1 = tc[1], t2 = tc[2];

        const float4* Sp = (const float4*)(S + ((size_t)b * Nn + A + L * 4) * 3);
        const float4 x0 = Sp[0], x1 = Sp[1], x2 = Sp[2];   // 4 rows, coalesced

        int found = 0x7FFFFFFF;
        // descending r: last write wins -> smallest r; then int-min across lanes.
        if (dist3(x2.y, x2.z, x2.w, t0, t1, t2) == m) found = A + L * 4 + 3;
        if (dist3(x1.z, x1.w, x2.x, t0, t1, t2) == m) found = A + L * 4 + 2;
        if (dist3(x0.w, x1.x, x1.y, t0, t1, t2) == m) found = A + L * 4 + 1;
        if (dist3(x0.x, x0.y, x0.z, t0, t1, t2) == m) found = A + L * 4 + 0;
        #pragma unroll
        for (int mask = 1; mask < 64; mask <<= 1)
            found = min(found, __shfl_xor(found, mask, 64));
        if (L == 0) out[2 + 2 * Nn + e] = (float)found;

        if (L == 0) red[tid >> 6] = m;
        __syncthreads();
        if (tid == 0) pc[blockIdx.x] = (red[0] + red[1]) + (red[2] + red[3]);
    } else {                 // ---- row mode ----
        const int j = (blockIdx.x - CB) * 256 + tid;   // [0, 16384)
        const int b = j >> 13;
        const int row = j & 8191;

        unsigned long long p = ws[j];
        const float dist = __uint_as_float((unsigned int)(p >> 32));
        const int cb = (int)(unsigned int)(p & 0xFFFFFFFFu);

        const float* Pp = S + ((size_t)b * Nn + row) * 3;
        const float s0 = Pp[0], s1 = Pp[1], s2 = Pp[2];
        const float4* Qb = (const float4*)(T + ((size_t)b * Nn + cb) * 3);  // cb%8==0 -> aligned
        const float4 y0 = Qb[0], y1 = Qb[1], y2 = Qb[2];
        const float4 y3 = Qb[3], y4 = Qb[4], y5 = Qb[5];

        int idx = cb;
        // descending t: last write wins -> smallest t attaining dist.
        if (dist3(s0, s1, s2, y5.y, y5.z, y5.w) == dist) idx = cb + 7;
        if (dist3(s0, s1, s2, y4.z, y4.w, y5.x) == dist) idx = cb + 6;
        if (dist3(s0, s1, s2, y3.w, y4.x, y4.y) == dist) idx = cb + 5;
        if (dist3(s0, s1, s2, y3.x, y3.y, y3.z) == dist) idx = cb + 4;
        if (dist3(s0, s1, s2, y2.y, y2.z, y2.w) == dist) idx = cb + 3;
        if (dist3(s0, s1, s2, y1.z, y1.w, y2.x) == dist) idx = cb + 2;
        if (dist3(s0, s1, s2, y0.w, y1.x, y1.y) == dist) idx = cb + 1;
        if (dist3(s0, s1, s2, y0.x, y0.y, y0.z) == dist) idx = cb + 0;
        out[2 + j] = (float)idx;

        float sum = dist;
        for (int off = 32; off > 0; off >>= 1) sum += __shfl_down(sum, off, 64);
        if ((tid & 63) == 0) red[tid >> 6] = sum;
        __syncthreads();
        if (tid == 0)
            pr[blockIdx.x - CB] = (red[0] + red[1]) + (red[2] + red[3]);
    }
}

// Deterministic parallel combine (fixed strided order).
__global__ __launch_bounds__(256) void cd_combine(const float* __restrict__ pr,
                                                  const float* __restrict__ pc,
                                                  float* __restrict__ out) {
    const int tid = threadIdx.x;
    float s1 = (tid < 64) ? pr[tid] : 0.0f;
    float s2 = 0.0f;
    for (int i = tid; i < CB; i += 256) s2 += pc[i];

    __shared__ float r1[4], r2[4];
    for (int off = 32; off > 0; off >>= 1) {
        s1 += __shfl_down(s1, off, 64);
        s2 += __shfl_down(s2, off, 64);
    }
    if ((tid & 63) == 0) { r1[tid >> 6] = s1; r2[tid >> 6] = s2; }
    __syncthreads();
    if (tid == 0) {
        out[0] = ((r1[0] + r1[1]) + (r1[2] + r1[3])) / (float)(Bn * Nn);
        out[1] = ((r2[0] + r2[1]) + (r2[2] + r2[3])) / (float)(Bn * Nn);
    }
}

// Fallback (no workspace): scan-all per query, direct writes + atomic loss.
static constexpr int FPTS = 256;
static constexpr int FCHUNK = 1024;

__global__ void cd_zero2(float* __restrict__ out) { out[0] = 0.0f; out[1] = 0.0f; }

__global__ __launch_bounds__(FPTS) void cd_dir_direct(const float* __restrict__ P,
                                                      const float* __restrict__ Q,
                                                      int nP, int nQ,
                                                      float* __restrict__ idx_out,
                                                      float* __restrict__ loss_out,
                                                      float inv_count) {
    __shared__ float lq[FCHUNK * 3];
    __shared__ float red[FPTS / 64];
    const int b = blockIdx.z;
    const int i = blockIdx.x * FPTS + threadIdx.x;
    const float* Pp = P + ((size_t)b * nP + i) * 3;
    const float s0 = Pp[0], s1 = Pp[1], s2 = Pp[2];

    float best = INFINITY;
    int bi = 0;
    for (int c = 0; c < nQ / FCHUNK; ++c) {
        __syncthreads();
        const float* Qb = Q + ((size_t)b * nQ + (size_t)c * FCHUNK) * 3;
        for (int j = threadIdx.x; j < FCHUNK * 3; j += FPTS) lq[j] = Qb[j];
        __syncthreads();
        #pragma unroll 4
        for (int m = 0; m < FCHUNK; ++m) {
            float dist = dist3(s0, s1, s2, lq[3 * m], lq[3 * m + 1], lq[3 * m + 2]);
            if (dist < best) { best = dist; bi = c * FCHUNK + m; }
        }
    }
    idx_out[(size_t)b * nP + i] = (float)bi;

    float v = best;
    for (int off = 32; off > 0; off >>= 1) v += __shfl_down(v, off, 64);
    const int wid = threadIdx.x >> 6;
    if ((threadIdx.x & 63) == 0) red[wid] = v;
    __syncthreads();
    if (threadIdx.x == 0) {
        float a = 0.0f;
        for (int w = 0; w < FPTS / 64; ++w) a += red[w];
        atomicAdd(loss_out, a * inv_count);
    }
}

extern "C" void kernel_launch(void* const* d_in, const int* in_sizes, int n_in,
                              void* d_out, int out_size, void* d_ws, size_t ws_size,
                              hipStream_t stream) {
    const float* src = (const float*)d_in[0];
    const float* tgt = (const float*)d_in[1];
    float* out = (float*)d_out;
    const int TOTAL = 2 * Bn * Nn;                         // 32768 packed entries
    const size_t need = (size_t)TOTAL * sizeof(unsigned long long)
                      + (64 + CB) * sizeof(float);

    if (ws_size >= need) {
        unsigned long long* ws = (unsigned long long*)d_ws;
        float* pr = (float*)(ws + TOTAL);                  // 64 row partials
        float* pc = pr + 64;                               // 4096 col partials
        cd_init<<<(TOTAL + 255) / 256, 256, 0, stream>>>(ws);
        cd_tile<<<dim3(Nn / RT, Nn / CT, Bn), THR, 0, stream>>>(src, tgt, ws);
        cd_fin<<<CB + 64, 256, 0, stream>>>(ws, src, tgt, out, pr, pc);
        cd_combine<<<1, 256, 0, stream>>>(pr, pc, out);
    } else {
        cd_zero2<<<1, 1, 0, stream>>>(out);
        cd_dir_direct<<<dim3(Nn / FPTS, 1, Bn), FPTS, 0, stream>>>(
            src, tgt, Nn, Nn, out + 2, out + 0, 1.0f / (float)(Bn * Nn));
        cd_dir_direct<<<dim3(Nn / FPTS, 1, Bn), FPTS, 0, stream>>>(
            tgt, src, Nn, Nn, out + 2 + Bn * Nn, out + 1, 1.0f / (float)(Bn * Nn));
    }
}

// Round 4
// 52.379 us; speedup vs baseline: 5.8860x; 1.0132x over previous
//
#include <hip/hip_runtime.h>
#include <math.h>

// Chamfer distance, B=2, N=M=8192, C=3, fp32 — FUSED: each d(s_i,t_j) computed once,
// feeding both row-min (src->tgt) and col-min (tgt->src).
// d_out (float32): [loss_src, loss_dst, indices1 (B*N), indices2 (B*M)]
// ws: u64[32768]: [0,16384) row packed (dist<<32|colBatchBase), [16384,32768) col packed
//     (dist<<32|rowAnchor); then float pr[64], pc[4096].
//
// NOTE (R1 post-mortem): do NOT fuse the final combine via a last-block ticket —
// per-block __threadfence() on multi-XCD gfx950 triggers an L2 writeback per block
// (4160 blocks -> 268 us). The kernel boundary is the cheap device-wide fence.
// NOTE (R2 post-mortem): CT=128 (1024 blocks = 4 blocks/CU) LOST 2 us vs CT=64
// (2048 blocks = 8 blocks/CU): occupancy beats atomic-traffic reduction. cd_tile is
// VALU-issue-bound (VALUBusy 72%, HBM 3%); shave instructions, keep waves high.
// NOTE (R3): __builtin_amdgcn_ds_swizzle pattern must be a compile-time constant at
// the call site -> template parameter, not a function argument.

static constexpr int Bn = 2;
static constexpr int Nn = 8192;
static constexpr int THR = 256;    // 4 waves per block
static constexpr int QPL = 4;      // rows per lane
static constexpr int RT = 1024;    // rows per block; wave w owns [rbase+256w, +256)
static constexpr int WROWS = 256;  // rows per wave (QPL*64)
static constexpr int CT = 64;      // cols staged per block (64 -> 8 blocks/CU, R2 lesson)
static constexpr int TB = 8;       // cols per register batch
static constexpr int CB = 4096;    // col-mode blocks in cd_fin (4 cols/block, 1 wave/col)

// ds_swizzle BitMode patterns: offset = (xor<<10) | (or<<5) | and, and=0x1F, or=0.
// Identical lane permutation to __shfl_xor(x, m, 64) for m < 32, but a single DS
// instruction with an immediate (no v_xor/v_lshl address math on the VALU pipe).
template <int PAT>
__device__ __forceinline__ float swzx(float x) {
    return __int_as_float(__builtin_amdgcn_ds_swizzle(__float_as_int(x), PAT));
}
static constexpr int SWZ_X1  = 0x041F;
static constexpr int SWZ_X2  = 0x081F;
static constexpr int SWZ_X4  = 0x101F;
static constexpr int SWZ_X8  = 0x201F;
static constexpr int SWZ_X16 = 0x401F;

__device__ __forceinline__ float dist3(float s0, float s1, float s2,
                                       float q0, float q1, float q2) {
    #pragma clang fp contract(off)
    float d0 = s0 - q0;
    float d1 = s1 - q1;
    float d2 = s2 - q2;
    return (d0 * d0 + d1 * d1) + d2 * d2;   // numpy-exact rounding order
}

__global__ void cd_init(unsigned long long* __restrict__ ws) {
    int i = blockIdx.x * blockDim.x + threadIdx.x;
    if (i < 2 * Bn * Nn) ws[i] = 0xFFFFFFFFFFFFFFFFULL;
}

__global__ __launch_bounds__(THR) void cd_tile(const float* __restrict__ S,
                                               const float* __restrict__ T,
                                               unsigned long long* __restrict__ ws) {
    const int b = blockIdx.z;
    const int rbase = blockIdx.x * RT;
    const int cbase = blockIdx.y * CT;
    unsigned long long* wsRow = ws + (size_t)b * Nn;
    unsigned long long* wsCol = ws + 2 * Nn + (size_t)b * Nn;

    __shared__ alignas(16) float lq[CT * 3];            // 192 floats
    __shared__ unsigned long long lwcol[4][CT];         // per-wave col minima, 2 KB
    if (threadIdx.x < CT * 3 / 4)                       // 48 float4 stores
        ((float4*)lq)[threadIdx.x] =
            ((const float4*)(T + ((size_t)b * Nn + cbase) * 3))[threadIdx.x];
    __syncthreads();

    const int w = threadIdx.x >> 6;
    const int L = threadIdx.x & 63;
    const int rowA = rbase + w * WROWS + L;        // + k*64, k<QPL
    const unsigned int anchor = (unsigned int)(rbase + w * WROWS);

    float q0[QPL], q1[QPL], q2[QPL];
    #pragma unroll
    for (int k = 0; k < QPL; ++k) {
        const float* p = S + ((size_t)b * Nn + rowA + k * 64) * 3;
        q0[k] = p[0]; q1[k] = p[1]; q2[k] = p[2];
    }

    float best[QPL];
    int bb[QPL];
    #pragma unroll
    for (int k = 0; k < QPL; ++k) { best[k] = INFINITY; bb[k] = 0; }

    const float4* lq4 = (const float4*)lq;
    #pragma unroll 2
    for (int jb = 0; jb < CT / TB; ++jb) {
        float4 v[6];                       // 24 floats = 8 target points
        #pragma unroll
        for (int j = 0; j < 6; ++j) v[j] = lq4[jb * 6 + j];

        float cm[TB];
        #define COMP(k) ((k & 3) == 0 ? v[(k) >> 2].x : \
                         (k & 3) == 1 ? v[(k) >> 2].y : \
                         (k & 3) == 2 ? v[(k) >> 2].z : v[(k) >> 2].w)
        #pragma unroll
        for (int k = 0; k < QPL; ++k) {
            float d[TB];
            #pragma unroll
            for (int t = 0; t < TB; ++t)
                d[t] = dist3(q0[k], q1[k], q2[k],
                             COMP(3 * t), COMP(3 * t + 1), COMP(3 * t + 2));
            // col side: running min over this lane's rows (exact fmin)
            #pragma unroll
            for (int t = 0; t < TB; ++t)
                cm[t] = (k == 0) ? d[t] : fminf(cm[t], d[t]);
            // row side: exact associative tree (shapes to v_min3) + strict <
            float m0 = fminf(fminf(d[0], d[1]), d[2]);
            float m1 = fminf(fminf(d[3], d[4]), d[5]);
            float m2 = fminf(d[6], d[7]);
            float bmin = fminf(fminf(m0, m1), m2);
            if (bmin < best[k]) { best[k] = bmin; bb[k] = cbase + jb * TB; }
        }
        #undef COMP

        // Fold-reduce 8 cols x 64 lanes -> lane L holds col 4*(L&1)+2*((L>>1)&1)+((L>>2)&1).
        // Exact: fmin only, any order gives the identical min value.
        // ds_swizzle immediates replace __shfl_xor (same permutation, fewer VALU ops).
        const bool u1 = (L & 1);
        float a0 = fminf(u1 ? cm[4] : cm[0], swzx<SWZ_X1>(u1 ? cm[0] : cm[4]));
        float a1 = fminf(u1 ? cm[5] : cm[1], swzx<SWZ_X1>(u1 ? cm[1] : cm[5]));
        float a2 = fminf(u1 ? cm[6] : cm[2], swzx<SWZ_X1>(u1 ? cm[2] : cm[6]));
        float a3 = fminf(u1 ? cm[7] : cm[3], swzx<SWZ_X1>(u1 ? cm[3] : cm[7]));
        const bool u2 = (L & 2);
        float b0 = fminf(u2 ? a2 : a0, swzx<SWZ_X2>(u2 ? a0 : a2));
        float b1 = fminf(u2 ? a3 : a1, swzx<SWZ_X2>(u2 ? a1 : a3));
        const bool u4 = (L & 4);
        float c0 = fminf(u4 ? b1 : b0, swzx<SWZ_X4>(u4 ? b0 : b1));
        c0 = fminf(c0, swzx<SWZ_X8>(c0));
        c0 = fminf(c0, swzx<SWZ_X16>(c0));
        c0 = fminf(c0, __shfl_xor(c0, 32, 64));

        if (L < TB) {
            const int c = 4 * (L & 1) + 2 * ((L >> 1) & 1) + ((L >> 2) & 1);
            unsigned long long pk =
                ((unsigned long long)__float_as_uint(c0) << 32) | anchor;
            // Per-wave slot, written exactly once per block -> plain store, no atomic.
            lwcol[w][jb * TB + c] = pk;
        }
    }

    // Row side: one device atomic per (row, col-block).
    #pragma unroll
    for (int k = 0; k < QPL; ++k) {
        unsigned long long pk =
            ((unsigned long long)__float_as_uint(best[k]) << 32) |
            (unsigned int)bb[k];
        atomicMin(&wsRow[rowA + k * 64], pk);
    }

    // Col side: cross-wave min in LDS, then ONE device atomic per col per block.
    __syncthreads();
    if (threadIdx.x < CT) {
        unsigned long long x0 = lwcol[0][threadIdx.x];
        unsigned long long x1 = lwcol[1][threadIdx.x];
        unsigned long long x2 = lwcol[2][threadIdx.x];
        unsigned long long x3 = lwcol[3][threadIdx.x];
        unsigned long long m01 = x0 < x1 ? x0 : x1;
        unsigned long long m23 = x2 < x3 ? x2 : x3;
        unsigned long long m = m01 < m23 ? m01 : m23;
        atomicMin(&wsCol[cbase + threadIdx.x], m);
    }
}

// Merged epilogue. Blocks [0,CB): col mode, 1 wave per col entry (coalesced float4
// scan of the 256-row anchor range). Blocks [CB, CB+64): row mode, 1 thread per row
// entry (float4 target batch, descending == scan).
__global__ __launch_bounds__(256) void cd_fin(const unsigned long long* __restrict__ ws,
                                              const float* __restrict__ S,
                                              const float* __restrict__ T,
                                              float* __restrict__ out,
                                              float* __restrict__ pr,
                                              float* __restrict__ pc) {
    __shared__ float red[4];
    const int tid = threadIdx.x;

    if (blockIdx.x < CB) {   // ---- col mode ----
        const int e = blockIdx.x * 4 + (tid >> 6);   // col entry [0, 16384)
        const int L = tid & 63;
        const int b = e >> 13;
        const int col = e & 8191;

        unsigned long long p = ws[2 * Nn + e];
        const float m = __uint_as_float((unsigned int)(p >> 32));
        const int A = (int)(unsigned int)(p & 0xFFFFFFFFu);

        const float* tc = T + ((size_t)b * Nn + col) * 3;
        const float t0 = tc[0], t1 = tc[1], t2 = tc[2];

        const float4* Sp = (const float4*)(S + ((size_t)b * Nn + A + L * 4) * 3);
        const float4 x0 = Sp[0], x1 = Sp[1], x2 = Sp[2];   // 4 rows, coalesced

        int found = 0x7FFFFFFF;
        // descending r: last write wins -> smallest r; then int-min across lanes.
        if (dist3(x2.y, x2.z, x2.w, t0, t1, t2) == m) found = A + L * 4 + 3;
        if (dist3(x1.z, x1.w, x2.x, t0, t1, t2) == m) found = A + L * 4 + 2;
        if (dist3(x0.w, x1.x, x1.y, t0, t1, t2) == m) found = A + L * 4 + 1;
        if (dist3(x0.x, x0.y, x0.z, t0, t1, t2) == m) found = A + L * 4 + 0;
        #pragma unroll
        for (int mask = 1; mask < 64; mask <<= 1)
            found = min(found, __shfl_xor(found, mask, 64));
        if (L == 0) out[2 + 2 * Nn + e] = (float)found;

        if (L == 0) red[tid >> 6] = m;
        __syncthreads();
        if (tid == 0) pc[blockIdx.x] = (red[0] + red[1]) + (red[2] + red[3]);
    } else {                 // ---- row mode ----
        const int j = (blockIdx.x - CB) * 256 + tid;   // [0, 16384)
        const int b = j >> 13;
        const int row = j & 8191;

        unsigned long long p = ws[j];
        const float dist = __uint_as_float((unsigned int)(p >> 32));
        const int cb = (int)(unsigned int)(p & 0xFFFFFFFFu);

        const float* Pp = S + ((size_t)b * Nn + row) * 3;
        const float s0 = Pp[0], s1 = Pp[1], s2 = Pp[2];
        const float4* Qb = (const float4*)(T + ((size_t)b * Nn + cb) * 3);  // cb%8==0 -> aligned
        const float4 y0 = Qb[0], y1 = Qb[1], y2 = Qb[2];
        const float4 y3 = Qb[3], y4 = Qb[4], y5 = Qb[5];

        int idx = cb;
        // descending t: last write wins -> smallest t attaining dist.
        if (dist3(s0, s1, s2, y5.y, y5.z, y5.w) == dist) idx = cb + 7;
        if (dist3(s0, s1, s2, y4.z, y4.w, y5.x) == dist) idx = cb + 6;
        if (dist3(s0, s1, s2, y3.w, y4.x, y4.y) == dist) idx = cb + 5;
        if (dist3(s0, s1, s2, y3.x, y3.y, y3.z) == dist) idx = cb + 4;
        if (dist3(s0, s1, s2, y2.y, y2.z, y2.w) == dist) idx = cb + 3;
        if (dist3(s0, s1, s2, y1.z, y1.w, y2.x) == dist) idx = cb + 2;
        if (dist3(s0, s1, s2, y0.w, y1.x, y1.y) == dist) idx = cb + 1;
        if (dist3(s0, s1, s2, y0.x, y0.y, y0.z) == dist) idx = cb + 0;
        out[2 + j] = (float)idx;

        float sum = dist;
        for (int off = 32; off > 0; off >>= 1) sum += __shfl_down(sum, off, 64);
        if ((tid & 63) == 0) red[tid >> 6] = sum;
        __syncthreads();
        if (tid == 0)
            pr[blockIdx.x - CB] = (red[0] + red[1]) + (red[2] + red[3]);
    }
}

// Deterministic parallel combine (fixed strided order).
__global__ __launch_bounds__(256) void cd_combine(const float* __restrict__ pr,
                                                  const float* __restrict__ pc,
                                                  float* __restrict__ out) {
    const int tid = threadIdx.x;
    float s1 = (tid < 64) ? pr[tid] : 0.0f;
    float s2 = 0.0f;
    for (int i = tid; i < CB; i += 256) s2 += pc[i];

    __shared__ float r1[4], r2[4];
    for (int off = 32; off > 0; off >>= 1) {
        s1 += __shfl_down(s1, off, 64);
        s2 += __shfl_down(s2, off, 64);
    }
    if ((tid & 63) == 0) { r1[tid >> 6] = s1; r2[tid >> 6] = s2; }
    __syncthreads();
    if (tid == 0) {
        out[0] = ((r1[0] + r1[1]) + (r1[2] + r1[3])) / (float)(Bn * Nn);
        out[1] = ((r2[0] + r2[1]) + (r2[2] + r2[3])) / (float)(Bn * Nn);
    }
}

// Fallback (no workspace): scan-all per query, direct writes + atomic loss.
static constexpr int FPTS = 256;
static constexpr int FCHUNK = 1024;

__global__ void cd_zero2(float* __restrict__ out) { out[0] = 0.0f; out[1] = 0.0f; }

__global__ __launch_bounds__(FPTS) void cd_dir_direct(const float* __restrict__ P,
                                                      const float* __restrict__ Q,
                                                      int nP, int nQ,
                                                      float* __restrict__ idx_out,
                                                      float* __restrict__ loss_out,
                                                      float inv_count) {
    __shared__ float lq[FCHUNK * 3];
    __shared__ float red[FPTS / 64];
    const int b = blockIdx.z;
    const int i = blockIdx.x * FPTS + threadIdx.x;
    const float* Pp = P + ((size_t)b * nP + i) * 3;
    const float s0 = Pp[0], s1 = Pp[1], s2 = Pp[2];

    float best = INFINITY;
    int bi = 0;
    for (int c = 0; c < nQ / FCHUNK; ++c) {
        __syncthreads();
        const float* Qb = Q + ((size_t)b * nQ + (size_t)c * FCHUNK) * 3;
        for (int j = threadIdx.x; j < FCHUNK * 3; j += FPTS) lq[j] = Qb[j];
        __syncthreads();
        #pragma unroll 4
        for (int m = 0; m < FCHUNK; ++m) {
            float dist = dist3(s0, s1, s2, lq[3 * m], lq[3 * m + 1], lq[3 * m + 2]);
            if (dist < best) { best = dist; bi = c * FCHUNK + m; }
        }
    }
    idx_out[(size_t)b * nP + i] = (float)bi;

    float v = best;
    for (int off = 32; off > 0; off >>= 1) v += __shfl_down(v, off, 64);
    const int wid = threadIdx.x >> 6;
    if ((threadIdx.x & 63) == 0) red[wid] = v;
    __syncthreads();
    if (threadIdx.x == 0) {
        float a = 0.0f;
        for (int w = 0; w < FPTS / 64; ++w) a += red[w];
        atomicAdd(loss_out, a * inv_count);
    }
}

extern "C" void kernel_launch(void* const* d_in, const int* in_sizes, int n_in,
                              void* d_out, int out_size, void* d_ws, size_t ws_size,
                              hipStream_t stream) {
    const float* src = (const float*)d_in[0];
    const float* tgt = (const float*)d_in[1];
    float* out = (float*)d_out;
    const int TOTAL = 2 * Bn * Nn;                         // 32768 packed entries
    const size_t need = (size_t)TOTAL * sizeof(unsigned long long)
                      + (64 + CB) * sizeof(float);

    if (ws_size >= need) {
        unsigned long long* ws = (unsigned long long*)d_ws;
        float* pr = (float*)(ws + TOTAL);                  // 64 row partials
        float* pc = pr + 64;                               // 4096 col partials
        cd_init<<<(TOTAL + 255) / 256, 256, 0, stream>>>(ws);
        cd_tile<<<dim3(Nn / RT, Nn / CT, Bn), THR, 0, stream>>>(src, tgt, ws);
        cd_fin<<<CB + 64, 256, 0, stream>>>(ws, src, tgt, out, pr, pc);
        cd_combine<<<1, 256, 0, stream>>>(pr, pc, out);
    } else {
        cd_zero2<<<1, 1, 0, stream>>>(out);
        cd_dir_direct<<<dim3(Nn / FPTS, 1, Bn), FPTS, 0, stream>>>(
            src, tgt, Nn, Nn, out + 2, out + 0, 1.0f / (float)(Bn * Nn));
        cd_dir_direct<<<dim3(Nn / FPTS, 1, Bn), FPTS, 0, stream>>>(
            tgt, src, Nn, Nn, out + 2 + Bn * Nn, out + 1, 1.0f / (float)(Bn * Nn));
    }
}